// Round 6
// baseline (164.642 us; speedup 1.0000x reference)
//
#include <hip/hip_runtime.h>
#include <hip/hip_bf16.h>
#include <hip/hip_fp16.h>
#include <cstddef>
#include <cstdint>

typedef __attribute__((ext_vector_type(8))) short bf16x8;
typedef __attribute__((ext_vector_type(4))) float f32x4;

#define MFMA16(a, b, c) __builtin_amdgcn_mfma_f32_16x16x32_bf16((a), (b), (c), 0, 0, 0)

static constexpr int B = 4, S = 512, HID = 768, NH = 12, HD = 64;
static constexpr int QKV_N = B * NH * S * HD;
static constexpr size_t SCORES_N = (size_t)B * NH * S * S;

__device__ __forceinline__ short f2bf(float f) {
  unsigned u = __builtin_bit_cast(unsigned, f);
  u += 0x7FFFu + ((u >> 16) & 1u);
  return (short)(u >> 16);
}
__device__ __forceinline__ float h2f(short s) {
  __half h = __builtin_bit_cast(__half, (unsigned short)s);
  return __half2float(h);
}
__device__ __forceinline__ bf16x8 ld_cvt8(const float* __restrict__ p) {
  float4 a = *reinterpret_cast<const float4*>(p);
  float4 b = *reinterpret_cast<const float4*>(p + 4);
  bf16x8 r;
  r[0] = f2bf(a.x); r[1] = f2bf(a.y); r[2] = f2bf(a.z); r[3] = f2bf(a.w);
  r[4] = f2bf(b.x); r[5] = f2bf(b.y); r[6] = f2bf(b.z); r[7] = f2bf(b.w);
  return r;
}
// nontemporal 16B load as native ext-vector (HIP float4 rejected by builtin)
__device__ __forceinline__ f32x4 ld4nt(const float* p) {
  return __builtin_nontemporal_load(reinterpret_cast<const f32x4*>(p));
}
__device__ __forceinline__ bf16x8 cvt8(f32x4 a, f32x4 b) {
  bf16x8 r;
  r[0] = f2bf(a[0]); r[1] = f2bf(a[1]); r[2] = f2bf(a[2]); r[3] = f2bf(a[3]);
  r[4] = f2bf(b[0]); r[5] = f2bf(b[1]); r[6] = f2bf(b[2]); r[7] = f2bf(b[3]);
  return r;
}

// ---------------------------------------------------------------------------
// K1: fused QKV projection.
//   mat 0 (q): normal layout [b][h][i][d] bf16 + FUSED qr = 0.125*q@Wr^T
//   mat 1 (k): normal layout
//   mat 2 (v): TRANSPOSED vT[b][h][d][j] bf16 (for LDS-free PV)
// ---------------------------------------------------------------------------
__global__ __launch_bounds__(256) void k_qkv(
    const float* __restrict__ x,
    const float* __restrict__ Wq, const float* __restrict__ bq,
    const float* __restrict__ Wk, const float* __restrict__ bk,
    const float* __restrict__ Wv, const float* __restrict__ bv,
    const float* __restrict__ Wr,
    short* __restrict__ qkv, short* __restrict__ qrb, short* __restrict__ vT) {
  __shared__ short As[64 * 40];
  __shared__ short Bs[64 * 40];
  __shared__ short qs[64 * 72];   // q-tile re-stage for fused qr (mat 0 only)
  const int m0 = blockIdx.x * 64;
  const int nt = blockIdx.y;
  const int mat = nt / 12;
  const int nc0 = (nt % 12) * 64;
  const float* __restrict__ W    = (mat == 0) ? Wq : (mat == 1) ? Wk : Wv;
  const float* __restrict__ bias = (mat == 0) ? bq : (mat == 1) ? bk : bv;
  short* __restrict__ outp = qkv + (size_t)mat * QKV_N;
  const int t = threadIdx.x;
  const int w = t >> 6, lane = t & 63;
  const int wm = (w >> 1) * 32, wn = (w & 1) * 32;
  const int lr = lane & 15, lk = lane >> 4;
  f32x4 acc[2][2] = {};
  for (int kk = 0; kk < 768; kk += 32) {
#pragma unroll
    for (int it = 0; it < 2; ++it) {
      int f = it * 256 + t;
      {
        int r = f >> 3, c4 = f & 7;
        float4 v = *reinterpret_cast<const float4*>(x + (size_t)(m0 + r) * 768 + kk + c4 * 4);
        short* d = &As[r * 40 + c4 * 4];
        d[0] = f2bf(v.x); d[1] = f2bf(v.y); d[2] = f2bf(v.z); d[3] = f2bf(v.w);
      }
      {
        int kr = f >> 4, c4 = f & 15;
        float4 v = *reinterpret_cast<const float4*>(W + (size_t)(kk + kr) * 768 + nc0 + c4 * 4);
        int c = c4 * 4;
        Bs[(c + 0) * 40 + kr] = f2bf(v.x);
        Bs[(c + 1) * 40 + kr] = f2bf(v.y);
        Bs[(c + 2) * 40 + kr] = f2bf(v.z);
        Bs[(c + 3) * 40 + kr] = f2bf(v.w);
      }
    }
    __syncthreads();
    bf16x8 a0 = *reinterpret_cast<const bf16x8*>(&As[(wm + lr) * 40 + lk * 8]);
    bf16x8 a1 = *reinterpret_cast<const bf16x8*>(&As[(wm + 16 + lr) * 40 + lk * 8]);
    bf16x8 b0 = *reinterpret_cast<const bf16x8*>(&Bs[(wn + lr) * 40 + lk * 8]);
    bf16x8 b1 = *reinterpret_cast<const bf16x8*>(&Bs[(wn + 16 + lr) * 40 + lk * 8]);
    acc[0][0] = MFMA16(a0, b0, acc[0][0]);
    acc[0][1] = MFMA16(a0, b1, acc[0][1]);
    acc[1][0] = MFMA16(a1, b0, acc[1][0]);
    acc[1][1] = MFMA16(a1, b1, acc[1][1]);
    __syncthreads();
  }
  const int b_ = m0 >> 9;       // batch (tile never straddles b: 512 % 64 == 0)
  if (mat == 2) {
    // v: write transposed vT[b][h][d][j]
#pragma unroll
    for (int mf = 0; mf < 2; ++mf)
#pragma unroll
      for (int nf = 0; nf < 2; ++nf) {
        int col = nc0 + wn + nf * 16 + lr;
        float bv_ = bias[col];
        int h = col >> 6, d = col & 63;
#pragma unroll
        for (int reg = 0; reg < 4; ++reg) {
          int j = (m0 + wm + mf * 16 + lk * 4 + reg) & 511;
          vT[((size_t)(b_ * NH + h) * HD + d) * S + j] = f2bf(acc[mf][nf][reg] + bv_);
        }
      }
    return;
  }
  // q / k: normal layout
#pragma unroll
  for (int mf = 0; mf < 2; ++mf)
#pragma unroll
    for (int nf = 0; nf < 2; ++nf) {
      int col = nc0 + wn + nf * 16 + lr;
      float bv_ = bias[col];
      int h = col >> 6, d = col & 63;
#pragma unroll
      for (int reg = 0; reg < 4; ++reg) {
        int mloc = wm + mf * 16 + lk * 4 + reg;
        int i = (m0 + mloc) & 511;
        short qv = f2bf(acc[mf][nf][reg] + bv_);
        outp[(size_t)((b_ * NH + h) * S + i) * HD + d] = qv;
        if (mat == 0) qs[mloc * 72 + d] = qv;
      }
    }
  if (mat == 0) {
    // fused qr = 0.125 * q_tile(64x64) @ Wr^T(64x64), head h0 = nc0/64
    const int h0 = nc0 >> 6;
    __syncthreads();
    f32x4 qacc[2][2] = {};
#pragma unroll
    for (int ks = 0; ks < 2; ++ks) {
      int k0 = ks * 32 + lk * 8;
      bf16x8 a0 = *reinterpret_cast<const bf16x8*>(&qs[(wm + lr) * 72 + k0]);
      bf16x8 a1 = *reinterpret_cast<const bf16x8*>(&qs[(wm + 16 + lr) * 72 + k0]);
      bf16x8 b0 = ld_cvt8(Wr + (size_t)(wn + lr) * 64 + k0);
      bf16x8 b1 = ld_cvt8(Wr + (size_t)(wn + 16 + lr) * 64 + k0);
      qacc[0][0] = MFMA16(a0, b0, qacc[0][0]);
      qacc[0][1] = MFMA16(a0, b1, qacc[0][1]);
      qacc[1][0] = MFMA16(a1, b0, qacc[1][0]);
      qacc[1][1] = MFMA16(a1, b1, qacc[1][1]);
    }
#pragma unroll
    for (int mf = 0; mf < 2; ++mf)
#pragma unroll
      for (int nf = 0; nf < 2; ++nf) {
        int r = wn + nf * 16 + lr;
#pragma unroll
        for (int reg = 0; reg < 4; ++reg) {
          int i = (m0 + wm + mf * 16 + lk * 4 + reg) & 511;
          qrb[((size_t)(b_ * NH + h0) * S + i) * 64 + r] = f2bf(qacc[mf][nf][reg] * 0.125f);
        }
      }
  }
}

// ---------------------------------------------------------------------------
// K3: qk scores -> f16, layout [b][i][h][j].
// s = 0.125*q.k + (1-g-e)*(-30000): masked -> exp==0; g+e==2 -> clamp-saturated.
// ---------------------------------------------------------------------------
__global__ __launch_bounds__(256) void k_qk(const short* __restrict__ q,
                                            const short* __restrict__ kmat,
                                            const float* __restrict__ graph,
                                            const float* __restrict__ endm,
                                            __half* __restrict__ sc) {
  const int j0 = blockIdx.x * 64, i0 = blockIdx.y * 64;
  const int bh = blockIdx.z;
  const int b = bh / NH, hh = bh % NH;
  const short* __restrict__ qp = q + (size_t)(bh * S) * HD;
  const short* __restrict__ kp = kmat + (size_t)(bh * S) * HD;
  const int t = threadIdx.x;
  const int w = t >> 6, lane = t & 63;
  const int wm = (w >> 1) * 32, wn = (w & 1) * 32;
  const int lr = lane & 15, lk = lane >> 4;
  f32x4 acc[2][2] = {};
#pragma unroll
  for (int ks = 0; ks < 2; ++ks) {
    int k0 = ks * 32 + lk * 8;
    bf16x8 a0 = *reinterpret_cast<const bf16x8*>(qp + (size_t)(i0 + wm + lr) * 64 + k0);
    bf16x8 a1 = *reinterpret_cast<const bf16x8*>(qp + (size_t)(i0 + wm + 16 + lr) * 64 + k0);
    bf16x8 b0 = *reinterpret_cast<const bf16x8*>(kp + (size_t)(j0 + wn + lr) * 64 + k0);
    bf16x8 b1 = *reinterpret_cast<const bf16x8*>(kp + (size_t)(j0 + wn + 16 + lr) * 64 + k0);
    acc[0][0] = MFMA16(a0, b0, acc[0][0]);
    acc[0][1] = MFMA16(a0, b1, acc[0][1]);
    acc[1][0] = MFMA16(a1, b0, acc[1][0]);
    acc[1][1] = MFMA16(a1, b1, acc[1][1]);
  }
#pragma unroll
  for (int mf = 0; mf < 2; ++mf)
#pragma unroll
    for (int nf = 0; nf < 2; ++nf) {
      int j = j0 + wn + nf * 16 + lr;
      float e = endm[b * S + j];
#pragma unroll
      for (int reg = 0; reg < 4; ++reg) {
        int i = i0 + wm + mf * 16 + lk * 4 + reg;
        float g = graph[(size_t)(b * S + i) * S + j];
        float s = acc[mf][nf][reg] * 0.125f + (1.0f - g - e) * (-30000.0f);
        sc[(((size_t)b * S + i) * NH + hh) * S + j] = __float2half(s);
      }
    }
}

// ---------------------------------------------------------------------------
// K4: per (b,i): s = sc + qr.rel^T; p = exp(min(s,80)); den-reduce; probs bf16.
// Scores slab (16KB) pre-staged into LDS with 64B/thread vector loads so the
// in-loop score read is an LDS hit, not an HBM-latency scalar load.
// ---------------------------------------------------------------------------
__global__ __launch_bounds__(256) void k_relsm(const short* __restrict__ qrb,
                                               const float* __restrict__ rel,
                                               const __half* __restrict__ sc,
                                               short* __restrict__ probs) {
  __shared__ short sq[16 * 520];   // [h][j] f16 bits
  __shared__ float den_lds[64];
  const int i = blockIdx.x, b = blockIdx.y;
  const int t = threadIdx.x;
  const int w = t >> 6, lane = t & 63;
  const int lr = lane & 15, fq = lane >> 4;
  // stage scores slab: thread t copies 64B (h = t>>4, j = (t&15)*32 .. +32)
  {
    const short* src = reinterpret_cast<const short*>(sc + ((size_t)(b * S) + i) * NH * S);
    int hh = t >> 4, js = (t & 15) * 32;
    const short* sp = src + (size_t)hh * S + js;   // h=12..15 over-reads into probs region (discarded)
    short* dp = &sq[hh * 520 + js];
#pragma unroll
    for (int c = 0; c < 4; ++c)
      *reinterpret_cast<bf16x8*>(dp + c * 8) = *reinterpret_cast<const bf16x8*>(sp + c * 8);
  }
  const int hA = (lr < NH) ? lr : 0;  // clamp pad A-rows (outputs discarded)
  const short* qrow = qrb + ((size_t)(b * NH + hA) * S + i) * 64;
  bf16x8 a0 = *reinterpret_cast<const bf16x8*>(qrow + fq * 8);
  bf16x8 a1 = *reinterpret_cast<const bf16x8*>(qrow + 32 + fq * 8);
  // per-lane base into this block's rel slab; advances 16 rows (1024 f) per tt
  const float* rp = rel + (((size_t)(b * S) + i) * S + (size_t)(w * 128 + lr)) * 64 + fq * 8;
  float p[8][4];
  float den[4] = {0.f, 0.f, 0.f, 0.f};
  f32x4 c0 = ld4nt(rp), c1 = ld4nt(rp + 4), c2 = ld4nt(rp + 32), c3 = ld4nt(rp + 36);
  __syncthreads();
#pragma unroll
  for (int tt = 0; tt < 8; ++tt) {
    f32x4 n0, n1, n2, n3;
    if (tt < 7) {
      const float* rn = rp + (size_t)(tt + 1) * 1024;
      n0 = ld4nt(rn); n1 = ld4nt(rn + 4); n2 = ld4nt(rn + 32); n3 = ld4nt(rn + 36);
    }
    bf16x8 b0 = cvt8(c0, c1), b1 = cvt8(c2, c3);
    f32x4 acc = {};
    acc = MFMA16(a0, b0, acc);
    acc = MFMA16(a1, b1, acc);
    const int j0 = w * 128 + tt * 16;
#pragma unroll
    for (int r = 0; r < 4; ++r) {
      int h = fq * 4 + r;
      float s = acc[r] + h2f(sq[h * 520 + j0 + lr]);
      float pe = __expf(fminf(s, 80.0f));
      den[r] += pe;
      p[tt][r] = pe;
    }
    if (tt < 7) { c0 = n0; c1 = n1; c2 = n2; c3 = n3; }
  }
#pragma unroll
  for (int r = 0; r < 4; ++r) {
    float d = den[r];
    d += __shfl_xor(d, 1); d += __shfl_xor(d, 2);
    d += __shfl_xor(d, 4); d += __shfl_xor(d, 8);
    den[r] = d;
  }
  if (lr == 0) {
#pragma unroll
    for (int r = 0; r < 4; ++r) den_lds[w * 16 + fq * 4 + r] = den[r];
  }
  __syncthreads();
  float invd[4];
#pragma unroll
  for (int r = 0; r < 4; ++r) {
    int h = fq * 4 + r;
    invd[r] = 1.0f / (den_lds[h] + den_lds[16 + h] + den_lds[32 + h] + den_lds[48 + h]);
  }
#pragma unroll
  for (int tt = 0; tt < 8; ++tt) {
    int j0 = w * 128 + tt * 16;
#pragma unroll
    for (int r = 0; r < 4; ++r) {
      int h = fq * 4 + r;
      if (h < NH)
        probs[((size_t)(b * NH + h) * S + i) * S + j0 + lr] = f2bf(p[tt][r] * invd[r]);
    }
  }
}

// ---------------------------------------------------------------------------
// K5: ctx = probs @ v via MFMA, LDS-FREE (v pre-transposed as vT[b,h,d,j]).
// Block = 32i x 64d per (b,h); 768 blocks, no barriers, deep ILP.
// ---------------------------------------------------------------------------
__global__ __launch_bounds__(256) void k_pv2(const short* __restrict__ probs,
                                             const short* __restrict__ vT,
                                             float* __restrict__ out) {
  const int i0 = blockIdx.x * 32;
  const int h = blockIdx.y, b = blockIdx.z;
  const short* __restrict__ pp  = probs + (size_t)((b * NH + h) * S) * S;
  const short* __restrict__ vtp = vT + (size_t)((b * NH + h) * HD) * S;
  const int t = threadIdx.x;
  const int w = t >> 6, lane = t & 63;
  const int wm = (w >> 1) * 16, wn = (w & 1) * 32;
  const int lr = lane & 15, lk = lane >> 4;
  f32x4 acc[2] = {};
#pragma unroll
  for (int j0 = 0; j0 < S; j0 += 64) {
#pragma unroll
    for (int ks = 0; ks < 2; ++ks) {
      int k0 = j0 + ks * 32 + lk * 8;
      bf16x8 a0 = *reinterpret_cast<const bf16x8*>(pp + (size_t)(i0 + wm + lr) * S + k0);
      bf16x8 b0 = *reinterpret_cast<const bf16x8*>(vtp + (size_t)(wn + lr) * S + k0);
      bf16x8 b1 = *reinterpret_cast<const bf16x8*>(vtp + (size_t)(wn + 16 + lr) * S + k0);
      acc[0] = MFMA16(a0, b0, acc[0]);
      acc[1] = MFMA16(a0, b1, acc[1]);
    }
  }
#pragma unroll
  for (int nf = 0; nf < 2; ++nf) {
    int d = wn + nf * 16 + lr;
#pragma unroll
    for (int reg = 0; reg < 4; ++reg) {
      int i = i0 + wm + lk * 4 + reg;
      out[((size_t)(b * S) + i) * HID + h * 64 + d] = acc[nf][reg];
    }
  }
}

// ---------------------------------------------------------------------------
extern "C" void kernel_launch(void* const* d_in, const int* in_sizes, int n_in,
                              void* d_out, int out_size, void* d_ws, size_t ws_size,
                              hipStream_t stream) {
  const float* x     = (const float*)d_in[0];
  const float* graph = (const float*)d_in[1];
  const float* endm  = (const float*)d_in[2];
  const float* rel   = (const float*)d_in[3];
  const float* Wq = (const float*)d_in[4];  const float* bq = (const float*)d_in[5];
  const float* Wk = (const float*)d_in[6];  const float* bk = (const float*)d_in[7];
  const float* Wv = (const float*)d_in[8];  const float* bv = (const float*)d_in[9];
  const float* Wr = (const float*)d_in[10]; // br dropped: softmax-invariant

  short* qb  = (short*)d_ws;
  short* kb  = qb + QKV_N;
  short* vTb = kb + QKV_N;                          // v transposed [b][h][d][j]
  short* qrb = vTb + QKV_N;
  __half* scores = (__half*)(qrb + QKV_N);          // f16, [b][i][h][j]
  short* probs   = (short*)(scores + SCORES_N);     // bf16, [b][h][i][j]
  const size_t need = (size_t)4 * QKV_N * 2 + SCORES_N * 2 + SCORES_N * 2;
  if (ws_size < need) return;

  k_qkv<<<dim3(32, 36), 256, 0, stream>>>(x, Wq, bq, Wk, bk, Wv, bv, Wr, qb, qrb, vTb);
  k_qk<<<dim3(8, 8, B * NH), 256, 0, stream>>>(qb, kb, graph, endm, scores);
  k_relsm<<<dim3(S, B), 256, 0, stream>>>(qrb, rel, scores, probs);
  k_pv2<<<dim3(16, NH, B), 256, 0, stream>>>(probs, vTb, (float*)d_out);
}